// Round 8
// baseline (925.836 us; speedup 1.0000x reference)
//
#include <hip/hip_runtime.h>
#include <math.h>

typedef __attribute__((ext_vector_type(8))) __bf16 bf16x8;
typedef __attribute__((ext_vector_type(4))) float f32x4;
typedef unsigned short u16;
typedef unsigned int u32;

#define MFMA16(a, b, c) __builtin_amdgcn_mfma_f32_16x16x32_bf16(a, b, c, 0, 0, 0)

__device__ __forceinline__ u16 f2bf(float f) {
    u32 u = __float_as_uint(f);
    return (u16)((u + 0x7fffu + ((u >> 16) & 1u)) >> 16);   // RNE
}
__device__ __forceinline__ float bf2f(u16 h) {
    return __uint_as_float(((u32)h) << 16);
}

// ---------------------------------------------------------------------------
// conv weights fp32 [oc][ic][ky][kx] -> bf16 hi/lo [s][oc'][ic] where
// oc' = q*32 + cc*4 + g  (orig oc = g*64 + q*8 + cc) -> each lane's f32x4
// accumulator holds all 4 gates of one channel.
__global__ __launch_bounds__(256) void k_wtrans2(const float* __restrict__ cw,
                                                 u16* __restrict__ whi,
                                                 u16* __restrict__ wlo) {
    int idx = blockIdx.x * 256 + threadIdx.x;
    if (idx >= 294912) return;
    int s   = idx >> 15;
    int ocp = (idx >> 7) & 255;
    int ic  = idx & 127;
    int q = ocp >> 5, cc = (ocp >> 2) & 7, g = ocp & 3;
    int oc = g * 64 + q * 8 + cc;
    float f = cw[oc * 1152 + ic * 9 + s];
    u16 hi = f2bf(f);
    whi[idx] = hi;
    wlo[idx] = f2bf(f - bf2f(hi));
}

// ---------------------------------------------------------------------------
// qkv weights fp32 -> bf16 hi/lo [o 0..191][c 0..63]
__global__ __launch_bounds__(256) void k_qkvw(
    const float* __restrict__ qw, const float* __restrict__ kw,
    const float* __restrict__ vw, u16* __restrict__ w2h, u16* __restrict__ w2l)
{
    int idx = blockIdx.x * 256 + threadIdx.x;
    if (idx >= 12288) return;
    int o = idx >> 6, c = idx & 63;
    float f = (o < 64) ? qw[o * 64 + c]
            : (o < 128) ? kw[(o - 64) * 64 + c]
                        : vw[(o - 128) * 64 + c];
    u16 hi = f2bf(f);
    w2h[idx] = hi;
    w2l[idx] = f2bf(f - bf2f(hi));
}

// ---------------------------------------------------------------------------
// MFMA QKV: per block one (bt, 64-n slice). X split hi/lo in LDS (swizzled),
// W split hi/lo from global (L1-hot, 48KB). 3-MFMA split products.
__global__ __launch_bounds__(256) void k_qkv2(
    const float* __restrict__ X,
    const u16* __restrict__ w2h, const u16* __restrict__ w2l,
    const float* __restrict__ qb, const float* __restrict__ kb,
    const float* __restrict__ vb,
    u16* __restrict__ qmat, u16* __restrict__ kmat, u16* __restrict__ vt)
{
    __shared__ u16 bhs[4096];   // [n][c^((n&7)<<3)]
    __shared__ u16 bls[4096];

    const int tid = threadIdx.x;
    const int ns = blockIdx.x;    // 0..15
    const int bt = blockIdx.y;    // 0..127
    const int b = bt >> 4, t = bt & 15;
    const int n0 = ns * 64;

    const float* xb = X + (size_t)b * 1048576 + (size_t)t * 1024 + n0;
    for (int i = tid; i < 4096; i += 256) {
        int c = i >> 6, n = i & 63;
        float f = xb[(size_t)c * 16384 + n];
        u16 hi = f2bf(f);
        u16 lo = f2bf(f - bf2f(hi));
        int ci = c ^ ((n & 7) << 3);
        bhs[n * 64 + ci] = hi;
        bls[n * 64 + ci] = lo;
    }
    __syncthreads();

    const int wv = tid >> 6, lane = tid & 63;
    const int l15 = lane & 15, l4 = lane >> 4;
    const int o0 = wv * 48;

    f32x4 acc[3][4];
#pragma unroll
    for (int ot = 0; ot < 3; ++ot)
#pragma unroll
        for (int nt = 0; nt < 4; ++nt) acc[ot][nt] = (f32x4){0.f, 0.f, 0.f, 0.f};

#pragma unroll
    for (int kk = 0; kk < 2; ++kk) {
        bf16x8 Ah[3], Al[3];
#pragma unroll
        for (int ot = 0; ot < 3; ++ot) {
            int off = (o0 + ot * 16 + l15) * 64 + kk * 32 + l4 * 8;
            Ah[ot] = *reinterpret_cast<const bf16x8*>(w2h + off);
            Al[ot] = *reinterpret_cast<const bf16x8*>(w2l + off);
        }
#pragma unroll
        for (int nt = 0; nt < 4; ++nt) {
            int n = nt * 16 + l15;
            int gran = (kk * 4 + l4) ^ (n & 7);
            bf16x8 Bh = *reinterpret_cast<const bf16x8*>(bhs + n * 64 + gran * 8);
            bf16x8 Bl = *reinterpret_cast<const bf16x8*>(bls + n * 64 + gran * 8);
#pragma unroll
            for (int ot = 0; ot < 3; ++ot) {
                acc[ot][nt] = MFMA16(Ah[ot], Bh, acc[ot][nt]);
                acc[ot][nt] = MFMA16(Ah[ot], Bl, acc[ot][nt]);
                acc[ot][nt] = MFMA16(Al[ot], Bh, acc[ot][nt]);
            }
        }
    }

#pragma unroll
    for (int ot = 0; ot < 3; ++ot) {
#pragma unroll
        for (int r = 0; r < 4; ++r) {
            int row = o0 + ot * 16 + l4 * 4 + r;
            float bias = (row < 64) ? qb[row]
                       : (row < 128) ? kb[row - 64] : vb[row - 128];
#pragma unroll
            for (int nt = 0; nt < 4; ++nt) {
                int col = n0 + nt * 16 + l15;
                u16 h = f2bf(acc[ot][nt][r] + bias);
                if (row < 64)
                    qmat[(size_t)bt * 65536 + (size_t)col * 64 + row] = h;
                else if (row < 128)
                    kmat[(size_t)bt * 65536 + (size_t)col * 64 + (row - 64)] = h;
                else
                    vt[(size_t)bt * 65536 + (size_t)(row - 128) * 1024 + col] = h;
            }
        }
    }
}

// ---------------------------------------------------------------------------
// MFMA attention, 512 threads (8 waves share one K/V staging). Grid 1024.
// Output: za padded [bt][34][34][128] (ch 0-63 = hi, 64-127 = lo).
// ntile==0 blocks also zero the 132-px pad ring of their bt.
__global__ __launch_bounds__(512, 2) void k_attn2(
    const u16* __restrict__ qmat, const u16* __restrict__ kmat,
    const u16* __restrict__ vt, u16* __restrict__ za)
{
    __shared__ char kl[16384];          // K tile [128 m][64 d] swizzled
    __shared__ char vl[16384];          // V tile [64 c][128 m] swizzled
    __shared__ u16 plds[8 * 16 * 40];   // per-wave P [16 n][40 m-stride]

    const int tid = threadIdx.x;
    const int id  = blockIdx.x;                 // 0..1023
    const int w   = (id & 7) * 128 + (id >> 3); // XCD owns 16 bt
    const int bt  = w >> 3;
    const int nt8 = w & 7;

    const int wv = tid >> 6, lane = tid & 63;
    const int l15 = lane & 15, l4 = lane >> 4;
    const int n0 = nt8 * 128 + wv * 16;

    const u16* qb_ = qmat + (size_t)bt * 65536;
    const u16* kb_ = kmat + (size_t)bt * 65536;
    const u16* vb_ = vt + (size_t)bt * 65536;
    u16* zab = za + (size_t)bt * 147968;

    // ring zero (pad cells of this bt) by the ntile==0 block
    if (nt8 == 0) {
        for (int j = tid; j < 2112; j += 512) {
            int pi = j >> 4, q16 = j & 15;
            int px = (pi < 34) ? pi
                   : (pi < 68) ? (33 * 34 + (pi - 34))
                               : ((1 + ((pi - 68) >> 1)) * 34 + ((pi - 68) & 1) * 33);
            *reinterpret_cast<uint4*>(zab + px * 128 + q16 * 8) =
                make_uint4(0u, 0u, 0u, 0u);
        }
    }

    bf16x8 qf0 = *reinterpret_cast<const bf16x8*>(qb_ + (n0 + l15) * 64 + l4 * 8);
    bf16x8 qf1 = *reinterpret_cast<const bf16x8*>(qb_ + (n0 + l15) * 64 + 32 + l4 * 8);

    f32x4 oacc[4];
#pragma unroll
    for (int ct = 0; ct < 4; ++ct) oacc[ct] = (f32x4){0.f, 0.f, 0.f, 0.f};
    float lsum = 0.f;
    char* plc = (char*)plds + wv * 1280;

    bf16x8 kst[2], vst[2];
#pragma unroll
    for (int r = 0; r < 2; ++r) {
        int c = tid + r * 512;
        kst[r] = *reinterpret_cast<const bf16x8*>(kb_ + (c >> 3) * 64 + (c & 7) * 8);
        vst[r] = *reinterpret_cast<const bf16x8*>(vb_ + (c >> 4) * 1024 + (c & 15) * 8);
    }

    for (int mt = 0; mt < 8; ++mt) {
        __syncthreads();
#pragma unroll
        for (int r = 0; r < 2; ++r) {
            int c = tid + r * 512;
            int m = c >> 3, sl = c & 7;
            *reinterpret_cast<bf16x8*>(kl + ((m * 128 + sl * 16) ^ ((m & 7) << 4))) = kst[r];
            int cc = c >> 4, sl2 = c & 15;
            *reinterpret_cast<bf16x8*>(vl + ((cc * 256 + sl2 * 16) ^ ((cc & 7) << 4))) = vst[r];
        }
        __syncthreads();
        if (mt < 7) {
            int mg = (mt + 1) * 128;
#pragma unroll
            for (int r = 0; r < 2; ++r) {
                int c = tid + r * 512;
                kst[r] = *reinterpret_cast<const bf16x8*>(kb_ + (mg + (c >> 3)) * 64 + (c & 7) * 8);
                vst[r] = *reinterpret_cast<const bf16x8*>(vb_ + (c >> 4) * 1024 + mg + (c & 15) * 8);
            }
        }

#pragma unroll
        for (int mi2 = 0; mi2 < 4; ++mi2) {
#pragma unroll
            for (int hf = 0; hf < 2; ++hf) {
                int ml = (mi2 * 2 + hf) * 16 + l15;
                f32x4 s = {0.f, 0.f, 0.f, 0.f};
                bf16x8 ka0 = *reinterpret_cast<const bf16x8*>(
                    kl + ((ml * 128 + l4 * 16) ^ ((ml & 7) << 4)));
                bf16x8 ka1 = *reinterpret_cast<const bf16x8*>(
                    kl + ((ml * 128 + 64 + l4 * 16) ^ ((ml & 7) << 4)));
                s = MFMA16(ka0, qf0, s);
                s = MFMA16(ka1, qf1, s);
                float p0 = __expf(s[0]);
                float p1 = __expf(s[1]);
                float p2 = __expf(s[2]);
                float p3 = __expf(s[3]);
                lsum += (p0 + p1) + (p2 + p3);
                u32 pa = (u32)f2bf(p0) | ((u32)f2bf(p1) << 16);
                u32 pb = (u32)f2bf(p2) | ((u32)f2bf(p3) << 16);
                *reinterpret_cast<uint2*>(plc + l15 * 80 + hf * 32 + l4 * 8) =
                    make_uint2(pa, pb);
            }
            bf16x8 pfrag = *reinterpret_cast<const bf16x8*>(plc + l15 * 80 + l4 * 16);
#pragma unroll
            for (int ct = 0; ct < 4; ++ct) {
                bf16x8 vfrag = *reinterpret_cast<const bf16x8*>(
                    vl + (((ct * 16 + l15) * 256 + mi2 * 64 + l4 * 16) ^ ((l15 & 7) << 4)));
                oacc[ct] = MFMA16(pfrag, vfrag, oacc[ct]);
            }
        }
    }

    lsum += __shfl_xor(lsum, 16, 64);
    lsum += __shfl_xor(lsum, 32, 64);

#pragma unroll
    for (int r = 0; r < 4; ++r) {
        float linv = 1.f / __shfl(lsum, l4 * 4 + r, 64);
        int nrow = n0 + l4 * 4 + r;
        u16* base = zab + (((nrow >> 5) + 1) * 34 + (nrow & 31) + 1) * 128;
#pragma unroll
        for (int ct = 0; ct < 4; ++ct) {
            float v = oacc[ct][r] * linv;
            u16 hi = f2bf(v);
            base[ct * 16 + l15]      = hi;
            base[64 + ct * 16 + l15] = f2bf(v - bf2f(hi));
        }
    }
}

// ---------------------------------------------------------------------------
// Fused conv+gates v6. Grid 256 (1 block/CU), 256 thr = 4 waves.
// Block = 64 ocp' (oq quarter) x 128 px (4 rows). Wave = 64 ocp x 32 px
// (r=4 oc-tiles, c=2 px-tiles) -> acc[4][2]; per s: 4 ds_reads feed 24 MFMA
// (LDS demand 1.6x port vs 3.2x in v3/4/5). A and B register-double-buffered
// one s ahead; z chunk prefetched across the barrier in regs.
__global__ __launch_bounds__(256) void k_cell6(
    const u16* __restrict__ za, const u16* __restrict__ zh_in,
    u16* __restrict__ zh_out, float* __restrict__ cst,
    const u16* __restrict__ whi, const u16* __restrict__ wlo,
    const float* __restrict__ conv_b,
    const float* __restrict__ wci, const float* __restrict__ wcf,
    const float* __restrict__ wco, float* __restrict__ out, int t)
{
    __shared__ __align__(16) char zt[26112];   // [204 px][128B] swizzled

    const int tid = threadIdx.x;
    const int id  = blockIdx.x;                  // 0..255
    const int w   = (id & 7) * 32 + (id >> 3);   // XCD owns one b
    const int b   = w >> 5;
    const int oq  = (w >> 3) & 3;
    const int ys  = w & 7;
    const int y0  = ys * 4;
    const int bt  = b * 16 + t;

    const int wv = tid >> 6, lane = tid & 63;    // wv = row within strip
    const int l15 = lane & 15, l4 = lane >> 4;

    const u16* zab = za + (size_t)bt * 147968;
    const u16* zhb = zh_in + (size_t)b * 147968;

    // staging precompute (ck-invariant): 1632 granules = 204 px x 8 slots
    int gp_[7], sb_[7], lo_[7];
    const int ng = (tid < 96) ? 7 : 6;
#pragma unroll
    for (int r = 0; r < 7; ++r) {
        int g = tid + r * 256;
        if (g >= 1632) g = 0;                    // dummy (masked by ng)
        int p = g >> 3, slot = g & 7;
        int ly = p / 34, col = p - ly * 34;
        gp_[r] = (y0 + ly) * 34 + col;
        sb_[r] = (slot < 4) ? slot * 8 : 64 + (slot - 4) * 8;
        lo_[r] = p * 128 + ((slot * 16) ^ ((p & 7) << 4));
    }

    f32x4 acc[4][2];
#pragma unroll
    for (int at = 0; at < 4; ++at)
#pragma unroll
        for (int nt = 0; nt < 2; ++nt) acc[at][nt] = (f32x4){0.f, 0.f, 0.f, 0.f};

    bf16x8 Ah[2][4], Al[2][4], Bh[2][2], Bl[2][2];

    auto loadA = [&](int set, int s, int ck) {
#pragma unroll
        for (int at = 0; at < 4; ++at) {
            size_t woff = (size_t)(s * 256 + oq * 64 + at * 16 + l15) * 128
                          + ck * 32 + l4 * 8;
            Ah[set][at] = *reinterpret_cast<const bf16x8*>(whi + woff);
            Al[set][at] = *reinterpret_cast<const bf16x8*>(wlo + woff);
        }
    };
    auto loadB = [&](int set, int s) {
        const int dy = s / 3 - 1, dx = s % 3 - 1;
#pragma unroll
        for (int nt = 0; nt < 2; ++nt) {
            int pxl = (wv + dy + 1) * 34 + nt * 16 + l15 + 1 + dx;
            int swz = (pxl & 7) << 4;
            Bh[set][nt] = *reinterpret_cast<const bf16x8*>(
                zt + pxl * 128 + ((l4 * 16) ^ swz));
            Bl[set][nt] = *reinterpret_cast<const bf16x8*>(
                zt + pxl * 128 + ((64 + l4 * 16) ^ swz));
        }
    };

    uint4 st[7];
    // prologue: chunk 0 (za, c0=0)
#pragma unroll
    for (int r = 0; r < 7; ++r)
        if (r < ng)
            st[r] = *reinterpret_cast<const uint4*>(zab + gp_[r] * 128 + sb_[r]);

    for (int ck = 0; ck < 4; ++ck) {
        __syncthreads();   // previous chunk's LDS reads done
#pragma unroll
        for (int r = 0; r < 7; ++r)
            if (r < ng) *reinterpret_cast<uint4*>(zt + lo_[r]) = st[r];
        __syncthreads();
        if (ck < 3) {      // prefetch next chunk during compute
            const u16* src = (ck + 1 < 2) ? zab : zhb;
            const int c0 = ((ck + 1) & 1) * 32;
#pragma unroll
            for (int r = 0; r < 7; ++r)
                if (r < ng)
                    st[r] = *reinterpret_cast<const uint4*>(src + gp_[r] * 128 + sb_[r] + c0);
        }

        loadA(0, 0, ck);
        loadB(0, 0);
#pragma unroll
        for (int s = 0; s < 9; ++s) {
            const int cur = s & 1, nxt = cur ^ 1;
            if (s < 8) { loadA(nxt, s + 1, ck); loadB(nxt, s + 1); }
#pragma unroll
            for (int at = 0; at < 4; ++at)
#pragma unroll
                for (int nt = 0; nt < 2; ++nt) {
                    acc[at][nt] = MFMA16(Ah[cur][at], Bh[cur][nt], acc[at][nt]);
                    acc[at][nt] = MFMA16(Ah[cur][at], Bl[cur][nt], acc[at][nt]);
                    acc[at][nt] = MFMA16(Al[cur][at], Bh[cur][nt], acc[at][nt]);
                }
        }
    }

    // gates: acc[at][nt] regs r = gates (i,f,g~,o) of ch, px (nt,l15), row wv
    u16* zho = zh_out + (size_t)b * 147968;
    const int y = y0 + wv;
#pragma unroll
    for (int at = 0; at < 4; ++at) {
        int ch = (oq * 2 + (at >> 1)) * 8 + (at & 1) * 4 + l4;
        float bi = conv_b[ch], bf = conv_b[64 + ch];
        float bg = conv_b[128 + ch], bo = conv_b[192 + ch];
#pragma unroll
        for (int nt = 0; nt < 2; ++nt) {
            int x = nt * 16 + l15;
            int n = y * 32 + x;
            float ci = acc[at][nt][0] + bi;
            float cf = acc[at][nt][1] + bf;
            float cg = acc[at][nt][2] + bg;
            float co = acc[at][nt][3] + bo;
            size_t si = ((size_t)b * 64 + ch) * 1024 + n;
            int pw_ = ch * 1024 + n;
            float cp = cst[si];
            float iv = 1.f / (1.f + __expf(-(ci + wci[pw_] * cp)));
            float fv = 1.f / (1.f + __expf(-(cf + wcf[pw_] * cp)));
            float nc = fv * cp + iv * tanhf(cg);
            float ov = 1.f / (1.f + __expf(-(co + wco[pw_] * nc)));
            float nh = ov * tanhf(nc);
            cst[si] = nc;
            out[(((size_t)b * 64 + ch) * 16 + t) * 1024 + n] = nh;
            u16 hhi = f2bf(nh);
            u16* zp = zho + ((y + 1) * 34 + (x + 1)) * 128;
            zp[ch]      = hhi;
            zp[64 + ch] = f2bf(nh - bf2f(hhi));
        }
    }
}

// ---------------------------------------------------------------------------
// ws layout (bytes), total ~96.3 MB
#define OB_Q    0ull
#define OB_K    16777216ull
#define OB_V    33554432ull
#define OB_ZA   50331648ull   // 128 * 1156 * 128 * 2 = 37,879,808
#define OB_ZH0  88211456ull   // 8 * 1156 * 128 * 2 = 2,367,488
#define OB_ZH1  90578944ull
#define OB_CST  92946432ull   // 2,097,152
#define OB_WHI  95043584ull   // 589,824
#define OB_WLO  95633408ull   // 589,824
#define OB_WQ2H 96223232ull   // 24,576
#define OB_WQ2L 96247808ull   // 24,576

extern "C" void kernel_launch(void* const* d_in, const int* in_sizes, int n_in,
                              void* d_out, int out_size, void* d_ws, size_t ws_size,
                              hipStream_t stream)
{
    const float* X   = (const float*)d_in[0];
    const float* qw  = (const float*)d_in[1];
    const float* qb  = (const float*)d_in[2];
    const float* kw  = (const float*)d_in[3];
    const float* kb  = (const float*)d_in[4];
    const float* vw  = (const float*)d_in[5];
    const float* vb  = (const float*)d_in[6];
    const float* cw  = (const float*)d_in[7];
    const float* cb  = (const float*)d_in[8];
    const float* wci = (const float*)d_in[9];
    const float* wcf = (const float*)d_in[10];
    const float* wco = (const float*)d_in[11];
    float* out = (float*)d_out;
    char* wsb  = (char*)d_ws;

    u16* qmat = (u16*)(wsb + OB_Q);
    u16* kmat = (u16*)(wsb + OB_K);
    u16* vt   = (u16*)(wsb + OB_V);
    u16* za   = (u16*)(wsb + OB_ZA);
    u16* zh0  = (u16*)(wsb + OB_ZH0);
    u16* zh1  = (u16*)(wsb + OB_ZH1);
    float* cst= (float*)(wsb + OB_CST);
    u16* whi  = (u16*)(wsb + OB_WHI);
    u16* wlo  = (u16*)(wsb + OB_WLO);
    u16* w2h  = (u16*)(wsb + OB_WQ2H);
    u16* w2l  = (u16*)(wsb + OB_WQ2L);

    hipMemsetAsync(zh0, 0, 6832128ull, stream);   // zh0 + zh1 + cst
    k_wtrans2<<<1152, 256, 0, stream>>>(cw, whi, wlo);
    k_qkvw<<<48, 256, 0, stream>>>(qw, kw, vw, w2h, w2l);
    k_qkv2<<<dim3(16, 128), 256, 0, stream>>>(X, w2h, w2l, qb, kb, vb,
                                              qmat, kmat, vt);
    k_attn2<<<1024, 512, 0, stream>>>(qmat, kmat, vt, za);

    for (int t = 0; t < 16; ++t) {
        u16* hin  = (t & 1) ? zh1 : zh0;
        u16* hout = (t & 1) ? zh0 : zh1;
        k_cell6<<<256, 256, 0, stream>>>(za, hin, hout, cst, whi, wlo,
                                         cb, wci, wcf, wco, out, t);
    }
}

// Round 10
// 722.585 us; speedup vs baseline: 1.2813x; 1.2813x over previous
//
#include <hip/hip_runtime.h>
#include <math.h>

typedef __attribute__((ext_vector_type(8))) __bf16 bf16x8;
typedef __attribute__((ext_vector_type(4))) float f32x4;
typedef unsigned short u16;
typedef unsigned int u32;

#define MFMA16(a, b, c) __builtin_amdgcn_mfma_f32_16x16x32_bf16(a, b, c, 0, 0, 0)

__device__ __forceinline__ u16 f2bf(float f) {
    u32 u = __float_as_uint(f);
    return (u16)((u + 0x7fffu + ((u >> 16) & 1u)) >> 16);   // RNE
}
__device__ __forceinline__ float bf2f(u16 h) {
    return __uint_as_float(((u32)h) << 16);
}

// direct global->LDS async copy, 16B per lane (dest = uniform base + lane*16)
__device__ __forceinline__ void gload16(const void* g, void* lds) {
    __builtin_amdgcn_global_load_lds(
        (const __attribute__((address_space(1))) unsigned int*)g,
        (__attribute__((address_space(3))) unsigned int*)lds, 16, 0, 0);
}

// ---------------------------------------------------------------------------
// conv weights fp32 [oc][ic][ky][kx] -> bf16 hi/lo [s][oc'][ic] where
// oc' = q*32 + cc*4 + g  (orig oc = g*64 + q*8 + cc) -> each lane's f32x4
// accumulator holds all 4 gates of one channel.
__global__ __launch_bounds__(256) void k_wtrans2(const float* __restrict__ cw,
                                                 u16* __restrict__ whi,
                                                 u16* __restrict__ wlo) {
    int idx = blockIdx.x * 256 + threadIdx.x;
    if (idx >= 294912) return;
    int s   = idx >> 15;
    int ocp = (idx >> 7) & 255;
    int ic  = idx & 127;
    int q = ocp >> 5, cc = (ocp >> 2) & 7, g = ocp & 3;
    int oc = g * 64 + q * 8 + cc;
    float f = cw[oc * 1152 + ic * 9 + s];
    u16 hi = f2bf(f);
    whi[idx] = hi;
    wlo[idx] = f2bf(f - bf2f(hi));
}

// ---------------------------------------------------------------------------
// qkv weights fp32 -> bf16 hi/lo [o 0..191][c 0..63]
__global__ __launch_bounds__(256) void k_qkvw(
    const float* __restrict__ qw, const float* __restrict__ kw,
    const float* __restrict__ vw, u16* __restrict__ w2h, u16* __restrict__ w2l)
{
    int idx = blockIdx.x * 256 + threadIdx.x;
    if (idx >= 12288) return;
    int o = idx >> 6, c = idx & 63;
    float f = (o < 64) ? qw[o * 64 + c]
            : (o < 128) ? kw[(o - 64) * 64 + c]
                        : vw[(o - 128) * 64 + c];
    u16 hi = f2bf(f);
    w2h[idx] = hi;
    w2l[idx] = f2bf(f - bf2f(hi));
}

// ---------------------------------------------------------------------------
// MFMA QKV: per block one (bt, 64-n slice). X split hi/lo in LDS (swizzled),
// W split hi/lo from global (L1-hot, 48KB). 3-MFMA split products.
__global__ __launch_bounds__(256) void k_qkv2(
    const float* __restrict__ X,
    const u16* __restrict__ w2h, const u16* __restrict__ w2l,
    const float* __restrict__ qb, const float* __restrict__ kb,
    const float* __restrict__ vb,
    u16* __restrict__ qmat, u16* __restrict__ kmat, u16* __restrict__ vt)
{
    __shared__ u16 bhs[4096];   // [n][c^((n&7)<<3)]
    __shared__ u16 bls[4096];

    const int tid = threadIdx.x;
    const int ns = blockIdx.x;    // 0..15
    const int bt = blockIdx.y;    // 0..127
    const int b = bt >> 4, t = bt & 15;
    const int n0 = ns * 64;

    const float* xb = X + (size_t)b * 1048576 + (size_t)t * 1024 + n0;
    for (int i = tid; i < 4096; i += 256) {
        int c = i >> 6, n = i & 63;
        float f = xb[(size_t)c * 16384 + n];
        u16 hi = f2bf(f);
        u16 lo = f2bf(f - bf2f(hi));
        int ci = c ^ ((n & 7) << 3);
        bhs[n * 64 + ci] = hi;
        bls[n * 64 + ci] = lo;
    }
    __syncthreads();

    const int wv = tid >> 6, lane = tid & 63;
    const int l15 = lane & 15, l4 = lane >> 4;
    const int o0 = wv * 48;

    f32x4 acc[3][4];
#pragma unroll
    for (int ot = 0; ot < 3; ++ot)
#pragma unroll
        for (int nt = 0; nt < 4; ++nt) acc[ot][nt] = (f32x4){0.f, 0.f, 0.f, 0.f};

#pragma unroll
    for (int kk = 0; kk < 2; ++kk) {
        bf16x8 Ah[3], Al[3];
#pragma unroll
        for (int ot = 0; ot < 3; ++ot) {
            int off = (o0 + ot * 16 + l15) * 64 + kk * 32 + l4 * 8;
            Ah[ot] = *reinterpret_cast<const bf16x8*>(w2h + off);
            Al[ot] = *reinterpret_cast<const bf16x8*>(w2l + off);
        }
#pragma unroll
        for (int nt = 0; nt < 4; ++nt) {
            int n = nt * 16 + l15;
            int gran = (kk * 4 + l4) ^ (n & 7);
            bf16x8 Bh = *reinterpret_cast<const bf16x8*>(bhs + n * 64 + gran * 8);
            bf16x8 Bl = *reinterpret_cast<const bf16x8*>(bls + n * 64 + gran * 8);
#pragma unroll
            for (int ot = 0; ot < 3; ++ot) {
                acc[ot][nt] = MFMA16(Ah[ot], Bh, acc[ot][nt]);
                acc[ot][nt] = MFMA16(Ah[ot], Bl, acc[ot][nt]);
                acc[ot][nt] = MFMA16(Al[ot], Bh, acc[ot][nt]);
            }
        }
    }

#pragma unroll
    for (int ot = 0; ot < 3; ++ot) {
#pragma unroll
        for (int r = 0; r < 4; ++r) {
            int row = o0 + ot * 16 + l4 * 4 + r;
            float bias = (row < 64) ? qb[row]
                       : (row < 128) ? kb[row - 64] : vb[row - 128];
#pragma unroll
            for (int nt = 0; nt < 4; ++nt) {
                int col = n0 + nt * 16 + l15;
                u16 h = f2bf(acc[ot][nt][r] + bias);
                if (row < 64)
                    qmat[(size_t)bt * 65536 + (size_t)col * 64 + row] = h;
                else if (row < 128)
                    kmat[(size_t)bt * 65536 + (size_t)col * 64 + (row - 64)] = h;
                else
                    vt[(size_t)bt * 65536 + (size_t)(row - 128) * 1024 + col] = h;
            }
        }
    }
}

// ---------------------------------------------------------------------------
// MFMA attention, 512 threads (8 waves share one K/V staging). Grid 1024.
// Output: za padded [bt][34][34][128] (ch 0-63 = hi, 64-127 = lo).
// ntile==0 blocks also zero the 132-px pad ring of their bt.
__global__ __launch_bounds__(512, 2) void k_attn2(
    const u16* __restrict__ qmat, const u16* __restrict__ kmat,
    const u16* __restrict__ vt, u16* __restrict__ za)
{
    __shared__ char kl[16384];          // K tile [128 m][64 d] swizzled
    __shared__ char vl[16384];          // V tile [64 c][128 m] swizzled
    __shared__ u16 plds[8 * 16 * 40];   // per-wave P [16 n][40 m-stride]

    const int tid = threadIdx.x;
    const int id  = blockIdx.x;                 // 0..1023
    const int w   = (id & 7) * 128 + (id >> 3); // XCD owns 16 bt
    const int bt  = w >> 3;
    const int nt8 = w & 7;

    const int wv = tid >> 6, lane = tid & 63;
    const int l15 = lane & 15, l4 = lane >> 4;
    const int n0 = nt8 * 128 + wv * 16;

    const u16* qb_ = qmat + (size_t)bt * 65536;
    const u16* kb_ = kmat + (size_t)bt * 65536;
    const u16* vb_ = vt + (size_t)bt * 65536;
    u16* zab = za + (size_t)bt * 147968;

    // ring zero (pad cells of this bt) by the ntile==0 block
    if (nt8 == 0) {
        for (int j = tid; j < 2112; j += 512) {
            int pi = j >> 4, q16 = j & 15;
            int px = (pi < 34) ? pi
                   : (pi < 68) ? (33 * 34 + (pi - 34))
                               : ((1 + ((pi - 68) >> 1)) * 34 + ((pi - 68) & 1) * 33);
            *reinterpret_cast<uint4*>(zab + px * 128 + q16 * 8) =
                make_uint4(0u, 0u, 0u, 0u);
        }
    }

    bf16x8 qf0 = *reinterpret_cast<const bf16x8*>(qb_ + (n0 + l15) * 64 + l4 * 8);
    bf16x8 qf1 = *reinterpret_cast<const bf16x8*>(qb_ + (n0 + l15) * 64 + 32 + l4 * 8);

    f32x4 oacc[4];
#pragma unroll
    for (int ct = 0; ct < 4; ++ct) oacc[ct] = (f32x4){0.f, 0.f, 0.f, 0.f};
    float lsum = 0.f;
    char* plc = (char*)plds + wv * 1280;

    bf16x8 kst[2], vst[2];
#pragma unroll
    for (int r = 0; r < 2; ++r) {
        int c = tid + r * 512;
        kst[r] = *reinterpret_cast<const bf16x8*>(kb_ + (c >> 3) * 64 + (c & 7) * 8);
        vst[r] = *reinterpret_cast<const bf16x8*>(vb_ + (c >> 4) * 1024 + (c & 15) * 8);
    }

    for (int mt = 0; mt < 8; ++mt) {
        __syncthreads();
#pragma unroll
        for (int r = 0; r < 2; ++r) {
            int c = tid + r * 512;
            int m = c >> 3, sl = c & 7;
            *reinterpret_cast<bf16x8*>(kl + ((m * 128 + sl * 16) ^ ((m & 7) << 4))) = kst[r];
            int cc = c >> 4, sl2 = c & 15;
            *reinterpret_cast<bf16x8*>(vl + ((cc * 256 + sl2 * 16) ^ ((cc & 7) << 4))) = vst[r];
        }
        __syncthreads();
        if (mt < 7) {
            int mg = (mt + 1) * 128;
#pragma unroll
            for (int r = 0; r < 2; ++r) {
                int c = tid + r * 512;
                kst[r] = *reinterpret_cast<const bf16x8*>(kb_ + (mg + (c >> 3)) * 64 + (c & 7) * 8);
                vst[r] = *reinterpret_cast<const bf16x8*>(vb_ + (c >> 4) * 1024 + mg + (c & 15) * 8);
            }
        }

#pragma unroll
        for (int mi2 = 0; mi2 < 4; ++mi2) {
#pragma unroll
            for (int hf = 0; hf < 2; ++hf) {
                int ml = (mi2 * 2 + hf) * 16 + l15;
                f32x4 s = {0.f, 0.f, 0.f, 0.f};
                bf16x8 ka0 = *reinterpret_cast<const bf16x8*>(
                    kl + ((ml * 128 + l4 * 16) ^ ((ml & 7) << 4)));
                bf16x8 ka1 = *reinterpret_cast<const bf16x8*>(
                    kl + ((ml * 128 + 64 + l4 * 16) ^ ((ml & 7) << 4)));
                s = MFMA16(ka0, qf0, s);
                s = MFMA16(ka1, qf1, s);
                float p0 = __expf(s[0]);
                float p1 = __expf(s[1]);
                float p2 = __expf(s[2]);
                float p3 = __expf(s[3]);
                lsum += (p0 + p1) + (p2 + p3);
                u32 pa = (u32)f2bf(p0) | ((u32)f2bf(p1) << 16);
                u32 pb = (u32)f2bf(p2) | ((u32)f2bf(p3) << 16);
                *reinterpret_cast<uint2*>(plc + l15 * 80 + hf * 32 + l4 * 8) =
                    make_uint2(pa, pb);
            }
            bf16x8 pfrag = *reinterpret_cast<const bf16x8*>(plc + l15 * 80 + l4 * 16);
#pragma unroll
            for (int ct = 0; ct < 4; ++ct) {
                bf16x8 vfrag = *reinterpret_cast<const bf16x8*>(
                    vl + (((ct * 16 + l15) * 256 + mi2 * 64 + l4 * 16) ^ ((l15 & 7) << 4)));
                oacc[ct] = MFMA16(pfrag, vfrag, oacc[ct]);
            }
        }
    }

    lsum += __shfl_xor(lsum, 16, 64);
    lsum += __shfl_xor(lsum, 32, 64);

#pragma unroll
    for (int r = 0; r < 4; ++r) {
        float linv = 1.f / __shfl(lsum, l4 * 4 + r, 64);
        int nrow = n0 + l4 * 4 + r;
        u16* base = zab + (((nrow >> 5) + 1) * 34 + (nrow & 31) + 1) * 128;
#pragma unroll
        for (int ct = 0; ct < 4; ++ct) {
            float v = oacc[ct][r] * linv;
            u16 hi = f2bf(v);
            base[ct * 16 + l15]      = hi;
            base[64 + ct * 16 + l15] = f2bf(v - bf2f(hi));
        }
    }
}

// ---------------------------------------------------------------------------
// Fused conv+gates v7b. Grid 256 (1 block/CU), 256 thr = 4 waves.
// ENTIRE 4-row strip (204 px x 128 ic x hi/lo = 102 KB) burst-loaded into LDS
// via global_load_lds (deep vmcnt pipeline), ONE barrier, then all 36 (ck,s)
// MFMA steps from LDS with no further barriers. Register dbuf parity is
// (ck+s)&1 with the ck loop FULLY UNROLLED (compile-time indices; 9 odd steps
// per ck flip parity across chunk boundaries -- the R8 bug).
__global__ __launch_bounds__(256) void k_cell7(
    const u16* __restrict__ za, const u16* __restrict__ zh_in,
    u16* __restrict__ zh_out, float* __restrict__ cst,
    const u16* __restrict__ whi, const u16* __restrict__ wlo,
    const float* __restrict__ conv_b,
    const float* __restrict__ wci, const float* __restrict__ wcf,
    const float* __restrict__ wco, float* __restrict__ out, int t)
{
    __shared__ __align__(16) char zt[104448];   // [204 px][512 B]

    const int tid = threadIdx.x;
    const int id  = blockIdx.x;                  // 0..255
    const int w   = (id & 7) * 32 + (id >> 3);   // XCD owns one b
    const int b   = w >> 5;
    const int oq  = (w >> 3) & 3;
    const int ys  = w & 7;
    const int y0  = ys * 4;
    const int bt  = b * 16 + t;

    const int wv = tid >> 6, lane = tid & 63;    // wv = row within strip
    const int l15 = lane & 15, l4 = lane >> 4;

    const u16* zab = za + (size_t)bt * 147968;
    const u16* zhb = zh_in + (size_t)b * 147968;

    // ---- burst staging: 6528 granules of 16B = 102 wave-iters of 64 lanes.
    // LDS granule j = i*64+lane (byte j*16): p = j>>5, slot sl = j&31.
    // Stored content = source granule sls = (sl&24) | ((sl^(p&7))&7):
    // bit4 = span (0=hi,1=lo), bit3 = za/zh, bits0-2 = ic-granule (XOR p&7).
    for (int i = wv; i < 102; i += 4) {
        int j = i * 64 + lane;
        int p = j >> 5, sl = j & 31;
        int sls = (sl & 24) | ((sl ^ (p & 7)) & 7);
        int ly = p / 34, col = p - ly * 34;
        int gp = (y0 + ly) * 34 + col;
        int span = (sls >> 4) & 1;
        int ic8 = sls & 15;
        const u16* src = ((ic8 < 8) ? zab : zhb) + gp * 128 + span * 64 + (ic8 & 7) * 8;
        gload16(src, zt + i * 1024);
    }
    __syncthreads();   // drains vmcnt; all 102 KB resident

    f32x4 acc[4][2];
#pragma unroll
    for (int at = 0; at < 4; ++at)
#pragma unroll
        for (int nt = 0; nt < 2; ++nt) acc[at][nt] = (f32x4){0.f, 0.f, 0.f, 0.f};

    bf16x8 Ah[2][4], Al[2][4], Bh[2][2], Bl[2][2];

    auto loadA = [&](int set, int s, int ck) {
#pragma unroll
        for (int at = 0; at < 4; ++at) {
            size_t woff = (size_t)(s * 256 + oq * 64 + at * 16 + l15) * 128
                          + ck * 32 + l4 * 8;
            Ah[set][at] = *reinterpret_cast<const bf16x8*>(whi + woff);
            Al[set][at] = *reinterpret_cast<const bf16x8*>(wlo + woff);
        }
    };
    auto loadB = [&](int set, int s, int ck) {
        const int dy = s / 3 - 1, dx = s % 3 - 1;
        const int gs = ck * 4 + l4;              // source granule (hi span)
#pragma unroll
        for (int nt = 0; nt < 2; ++nt) {
            int pxl = (wv + dy + 1) * 34 + nt * 16 + l15 + 1 + dx;
            int sl = (gs & 8) | ((gs ^ (pxl & 7)) & 7);
            const char* bp = zt + pxl * 512 + sl * 16;
            Bh[set][nt] = *reinterpret_cast<const bf16x8*>(bp);
            Bl[set][nt] = *reinterpret_cast<const bf16x8*>(bp + 256);
        }
    };

    loadA(0, 0, 0);
    loadB(0, 0, 0);
#pragma unroll
    for (int ck = 0; ck < 4; ++ck) {
#pragma unroll
        for (int s = 0; s < 9; ++s) {
            const int cur = (ck + s) & 1, nxt = cur ^ 1;   // total-step parity
            if (s < 8)      { loadA(nxt, s + 1, ck); loadB(nxt, s + 1, ck); }
            else if (ck < 3){ loadA(nxt, 0, ck + 1); loadB(nxt, 0, ck + 1); }
#pragma unroll
            for (int at = 0; at < 4; ++at)
#pragma unroll
                for (int nt = 0; nt < 2; ++nt) {
                    acc[at][nt] = MFMA16(Ah[cur][at], Bh[cur][nt], acc[at][nt]);
                    acc[at][nt] = MFMA16(Ah[cur][at], Bl[cur][nt], acc[at][nt]);
                    acc[at][nt] = MFMA16(Al[cur][at], Bh[cur][nt], acc[at][nt]);
                }
        }
    }

    // gates: acc[at][nt] regs r = gates (i,f,g~,o) of ch, px (nt,l15), row wv
    u16* zho = zh_out + (size_t)b * 147968;
    const int y = y0 + wv;
#pragma unroll
    for (int at = 0; at < 4; ++at) {
        int ch = (oq * 2 + (at >> 1)) * 8 + (at & 1) * 4 + l4;
        float bi = conv_b[ch], bf = conv_b[64 + ch];
        float bg = conv_b[128 + ch], bo = conv_b[192 + ch];
#pragma unroll
        for (int nt = 0; nt < 2; ++nt) {
            int x = nt * 16 + l15;
            int n = y * 32 + x;
            float ci = acc[at][nt][0] + bi;
            float cf = acc[at][nt][1] + bf;
            float cg = acc[at][nt][2] + bg;
            float co = acc[at][nt][3] + bo;
            size_t si = ((size_t)b * 64 + ch) * 1024 + n;
            int pw_ = ch * 1024 + n;
            float cp = cst[si];
            float iv = 1.f / (1.f + __expf(-(ci + wci[pw_] * cp)));
            float fv = 1.f / (1.f + __expf(-(cf + wcf[pw_] * cp)));
            float nc = fv * cp + iv * tanhf(cg);
            float ov = 1.f / (1.f + __expf(-(co + wco[pw_] * nc)));
            float nh = ov * tanhf(nc);
            cst[si] = nc;
            out[(((size_t)b * 64 + ch) * 16 + t) * 1024 + n] = nh;
            u16 hhi = f2bf(nh);
            u16* zp = zho + ((y + 1) * 34 + (x + 1)) * 128;
            zp[ch]      = hhi;
            zp[64 + ch] = f2bf(nh - bf2f(hhi));
        }
    }
}

// ---------------------------------------------------------------------------
// ws layout (bytes), total ~96.3 MB
#define OB_Q    0ull
#define OB_K    16777216ull
#define OB_V    33554432ull
#define OB_ZA   50331648ull   // 128 * 1156 * 128 * 2 = 37,879,808
#define OB_ZH0  88211456ull   // 8 * 1156 * 128 * 2 = 2,367,488
#define OB_ZH1  90578944ull
#define OB_CST  92946432ull   // 2,097,152
#define OB_WHI  95043584ull   // 589,824
#define OB_WLO  95633408ull   // 589,824
#define OB_WQ2H 96223232ull   // 24,576
#define OB_WQ2L 96247808ull   // 24,576

extern "C" void kernel_launch(void* const* d_in, const int* in_sizes, int n_in,
                              void* d_out, int out_size, void* d_ws, size_t ws_size,
                              hipStream_t stream)
{
    const float* X   = (const float*)d_in[0];
    const float* qw  = (const float*)d_in[1];
    const float* qb  = (const float*)d_in[2];
    const float* kw  = (const float*)d_in[3];
    const float* kb  = (const float*)d_in[4];
    const float* vw  = (const float*)d_in[5];
    const float* vb  = (const float*)d_in[6];
    const float* cw  = (const float*)d_in[7];
    const float* cb  = (const float*)d_in[8];
    const float* wci = (const float*)d_in[9];
    const float* wcf = (const float*)d_in[10];
    const float* wco = (const float*)d_in[11];
    float* out = (float*)d_out;
    char* wsb  = (char*)d_ws;

    u16* qmat = (u16*)(wsb + OB_Q);
    u16* kmat = (u16*)(wsb + OB_K);
    u16* vt   = (u16*)(wsb + OB_V);
    u16* za   = (u16*)(wsb + OB_ZA);
    u16* zh0  = (u16*)(wsb + OB_ZH0);
    u16* zh1  = (u16*)(wsb + OB_ZH1);
    float* cst= (float*)(wsb + OB_CST);
    u16* whi  = (u16*)(wsb + OB_WHI);
    u16* wlo  = (u16*)(wsb + OB_WLO);
    u16* w2h  = (u16*)(wsb + OB_WQ2H);
    u16* w2l  = (u16*)(wsb + OB_WQ2L);

    hipMemsetAsync(zh0, 0, 6832128ull, stream);   // zh0 + zh1 + cst
    k_wtrans2<<<1152, 256, 0, stream>>>(cw, whi, wlo);
    k_qkvw<<<48, 256, 0, stream>>>(qw, kw, vw, w2h, w2l);
    k_qkv2<<<dim3(16, 128), 256, 0, stream>>>(X, w2h, w2l, qb, kb, vb,
                                              qmat, kmat, vt);
    k_attn2<<<1024, 512, 0, stream>>>(qmat, kmat, vt, za);

    for (int t = 0; t < 16; ++t) {
        u16* hin  = (t & 1) ? zh1 : zh0;
        u16* hout = (t & 1) ? zh0 : zh1;
        k_cell7<<<256, 256, 0, stream>>>(za, hin, hout, cst, whi, wlo,
                                         cb, wci, wcf, wco, out, t);
    }
}